// Round 6
// baseline (3660.814 us; speedup 1.0000x reference)
//
#include <hip/hip_runtime.h>
#include <hip/hip_bf16.h>

#define BB 64
#define EE 512
#define HH 1024
#define KK 1536
#define VV 50257
#define SS 512

#define NWG 64     // merged blocks: mi = bid&3 (16 rows), ni = bid>>2 (16 col-tiles)
#define RING 8
#define PADU 32    // unsigned per flag slot = 128 B line

typedef __bf16 bf16x8 __attribute__((ext_vector_type(8)));
typedef float f32x4 __attribute__((ext_vector_type(4)));

__device__ __forceinline__ bf16x8 load_bf8(const __bf16* p) {
    return *reinterpret_cast<const bf16x8*>(p);
}

__device__ __forceinline__ bf16x8 cvt8(const float* p) {
    f32x4 a = *reinterpret_cast<const f32x4*>(p);
    f32x4 b = *reinterpret_cast<const f32x4*>(p + 4);
    bf16x8 r;
    r[0] = (__bf16)a[0]; r[1] = (__bf16)a[1]; r[2] = (__bf16)a[2]; r[3] = (__bf16)a[3];
    r[4] = (__bf16)b[0]; r[5] = (__bf16)b[1]; r[6] = (__bf16)b[2]; r[7] = (__bf16)b[3];
    return r;
}

// Coherent (agent-scope, relaxed) loads/stores: routed to the coherence point,
// no cache-maintenance instructions ever.
__device__ __forceinline__ unsigned long long ld8c(const void* p) {
    return __hip_atomic_load((unsigned long long*)p, __ATOMIC_RELAXED,
                             __HIP_MEMORY_SCOPE_AGENT);
}
__device__ __forceinline__ void st8c(void* p, unsigned long long v) {
    __hip_atomic_store((unsigned long long*)p, v, __ATOMIC_RELAXED,
                       __HIP_MEMORY_SCOPE_AGENT);
}
__device__ __forceinline__ void st4c(void* p, unsigned v) {
    __hip_atomic_store((unsigned*)p, v, __ATOMIC_RELAXED, __HIP_MEMORY_SCOPE_AGENT);
}
__device__ __forceinline__ bf16x8 load_bf8_coh(const __bf16* p) {
    union { unsigned long long u[2]; bf16x8 v; } t;
    t.u[0] = ld8c(p);
    t.u[1] = ld8c(p + 4);
    return t.v;
}
__device__ __forceinline__ unsigned long long pack4(float s0, float s1, float s2, float s3) {
    union { __bf16 h[4]; unsigned long long u; } t;
    t.h[0] = (__bf16)s0; t.h[1] = (__bf16)s1; t.h[2] = (__bf16)s2; t.h[3] = (__bf16)s3;
    return t.u;
}
__device__ __forceinline__ unsigned pack2(float s0, float s1) {
    union { __bf16 h[2]; unsigned u; } t;
    t.h[0] = (__bf16)s0; t.h[1] = (__bf16)s1;
    return t.u;
}

// Per-wave wait: 64 lanes poll 64 flag slots (each on its own 128B line).
__device__ __forceinline__ void wait64(const unsigned* slots, unsigned target) {
    const int l = threadIdx.x & 63;
    for (;;) {
        unsigned v = __hip_atomic_load(&slots[l * PADU], __ATOMIC_RELAXED,
                                       __HIP_MEMORY_SCOPE_AGENT);
        if (__all((int)(v >= target))) break;
    }
    asm volatile("" ::: "memory");
}

// Wave-parallel min over the 64 slots (broadcast to all lanes).
__device__ __forceinline__ unsigned min64(const unsigned* slots) {
    const int l = threadIdx.x & 63;
    unsigned v = __hip_atomic_load(&slots[l * PADU], __ATOMIC_RELAXED,
                                   __HIP_MEMORY_SCOPE_AGENT);
    #pragma unroll
    for (int o = 32; o; o >>= 1) {
        unsigned u = (unsigned)__shfl_xor((int)v, o, 64);
        v = u < v ? u : v;
    }
    return v;
}

// Per-wave publish: this wave's global stores acked, then flag store.
__device__ __forceinline__ void wsignal(unsigned* slot, unsigned val) {
    asm volatile("s_waitcnt vmcnt(0)" ::: "memory");
    if ((threadIdx.x & 63) == 0)
        __hip_atomic_store(slot, val, __ATOMIC_RELAXED, __HIP_MEMORY_SCOPE_AGENT);
}

// Decode tokens to int32 (auto-detect int64 vs int32) + zero the flag slots.
__global__ void tokens_kernel(const void* __restrict__ seq, int* __restrict__ tok,
                              unsigned* __restrict__ bar) {
    int z = blockIdx.x * 256 + threadIdx.x;
    if (z < 4 * 2 * 64 * PADU)
        __hip_atomic_store(&bar[z], 0u, __ATOMIC_RELAXED, __HIP_MEMORY_SCOPE_AGENT);
    const unsigned* u = (const unsigned*)seq;
    bool is64 = true;
    #pragma unroll 1
    for (int i = 0; i < 64; ++i) {
        if (u[2 * i + 1] != 0u) { is64 = false; break; }
    }
    int i = blockIdx.x * 256 + threadIdx.x;
    if (i < BB * SS) tok[i] = is64 ? (int)u[2 * i] : (int)u[i];
}

// fp32 [R][C] row-major -> bf16 [C][R]
__global__ __launch_bounds__(256) void transpose_kernel(
    const float* __restrict__ in, __bf16* __restrict__ out, int R, int C) {
    __shared__ float t[32][33];
    int bc = C >> 5;
    int br = blockIdx.x / bc;
    int bco = blockIdx.x % bc;
    int R0 = br << 5, C0 = bco << 5;
    int c = threadIdx.x & 31, r0 = threadIdx.x >> 5;
    #pragma unroll
    for (int i = 0; i < 4; ++i) {
        int r = r0 + i * 8;
        t[r][c] = in[(size_t)(R0 + r) * C + C0 + c];
    }
    __syncthreads();
    #pragma unroll
    for (int i = 0; i < 4; ++i) {
        int r = r0 + i * 8;
        out[(size_t)(C0 + r) * R + R0 + c] = (__bf16)t[c][r];
    }
}

__global__ void init_kernel(const float* __restrict__ h1, const float* __restrict__ h2,
                            __bf16* __restrict__ h1bf, __bf16* __restrict__ h2bf) {
    int i = blockIdx.x * 256 + threadIdx.x;
    if (i < BB * HH) h1bf[i] = (__bf16)h1[i];
    if (i < BB * EE) h2bf[i] = (__bf16)h2[i];
}

// Persistent merged-role recurrence with per-wave decoupled signaling.
// Block (mi,ni), iteration i:
//   G1 (i<SS):  h1_{i+1} tile [16x64] = tanh([e_i, h1_i] W1); per-wave f1:=i+1
//               signaled right after that wave's h1 rows drain (G2 tail + next
//               step's emb MFMAs overlap the flag propagation/detect).
//   G2 (i>=1):  h2_i tile [16x32] = tanh([h1_i, h2_{i-1}] W2); per-wave f2:=i.
// Ring depth 8; WAR covered by cached lag check f2min >= i-7 (re-polled only
// when the cache falls behind -> amortized ~0).
// Ordering proofs: SYNC1(i+1) happens-after every red2-read(i) (program order
// per wave); X's red-write(i+1) is gated by f1[Y]>=i+1 which Y sets after its
// red-read(i). Flags/h-state move via relaxed agent-scope atomics only.
__global__ __launch_bounds__(256, 1) void rnn_persist2(
    const int* __restrict__ tok32, const float* __restrict__ embW,
    const float* __restrict__ b1, const float* __restrict__ b2,
    const __bf16* __restrict__ W1t, const __bf16* __restrict__ W2t,
    __bf16* __restrict__ h1r, __bf16* __restrict__ h2r,
    float* __restrict__ h1out, float* __restrict__ h2out,
    unsigned* __restrict__ bar) {
    const int bid = blockIdx.x;
    const int mi = bid & 3;
    const int ni = bid >> 2;
    const int m0 = mi << 4;
    const int n0 = ni << 6;      // G1 column tile
    const int n20 = ni << 5;     // G2 column tile
    const int tid = threadIdx.x;
    const int w = tid >> 6;
    const int l = tid & 63;
    const int l16 = l & 15;
    const int kg = l >> 4;
    unsigned* f1s = bar + mi * (2 * 64 * PADU);
    unsigned* f2s = f1s + 64 * PADU;
    unsigned* myf1 = &f1s[(ni * 4 + w) * PADU];
    unsigned* myf2 = &f2s[(ni * 4 + w) * PADU];

    __shared__ int tok_s[SS][16];
    __shared__ float red[4][16][68];    // 16B-aligned rows (68*4=272)
    __shared__ float red2[4][16][68];

    for (int idx = tid; idx < SS * 16; idx += 256) {
        int t = idx >> 4, r = idx & 15;
        tok_s[t][r] = tok32[(m0 + r) * SS + t];
    }

    // Register-resident weights: wave w holds K-slices {w+4t, t=0..11}.
    bf16x8 wg1[12][4];
    bf16x8 wg2[12][2];
    #pragma unroll
    for (int t = 0; t < 12; ++t) {
        const int kb = 32 * (w + 4 * t) + kg * 8;
        #pragma unroll
        for (int nf = 0; nf < 4; ++nf)
            wg1[t][nf] = load_bf8(W1t + (size_t)(n0 + nf * 16 + l16) * KK + kb);
        #pragma unroll
        for (int nf = 0; nf < 2; ++nf)
            wg2[t][nf] = load_bf8(W2t + (size_t)(n20 + nf * 16 + l16) * KK + kb);
    }
    {   // Pin in the register file (round-3 lesson).
        f32x4* p1 = reinterpret_cast<f32x4*>(&wg1[0][0]);
        #pragma unroll
        for (int q = 0; q < 48; ++q) asm volatile("" : "+v"(p1[q]));
        f32x4* p2 = reinterpret_cast<f32x4*>(&wg2[0][0]);
        #pragma unroll
        for (int q = 0; q < 24; ++q) asm volatile("" : "+v"(p2[q]));
    }

    // Per-wave epilogue mapping: row = 4w + (l>>4); G1 cols c1 = (l&15)*4,
    // G2 cols c2 = (l&15)*2.
    const int erow_ = 4 * w + (l >> 4);
    const int c1 = (l & 15) * 4;
    const int c2 = (l & 15) * 2;
    const f32x4 bb1 = *reinterpret_cast<const f32x4*>(b1 + n0 + c1);
    const float b2a = b2[n20 + c2];
    const float b2b = b2[n20 + c2 + 1];

    unsigned f2c = 0;  // cached min of f2 flags

    __syncthreads();

    for (int i = 0; i <= SS; ++i) {
        const __bf16* h1i = h1r + (size_t)(i & 7) * BB * HH;        // h1_i
        __bf16*       h1n = h1r + (size_t)((i + 1) & 7) * BB * HH;  // h1_{i+1}
        const __bf16* h2p = h2r + (size_t)((i + 7) & 7) * BB * EE;  // h2_{i-1}
        __bf16*       h2n = h2r + (size_t)(i & 7) * BB * EE;        // h2_i

        f32x4 acc1[4] = {{0,0,0,0},{0,0,0,0},{0,0,0,0},{0,0,0,0}};
        if (i < SS) {
            // Pre-wait: embedding-part MFMAs (cached path) — overlaps the
            // other blocks' tails and our flag detect.
            const float* er = embW + (size_t)tok_s[i][l16] * EE;
            #pragma unroll
            for (int t = 0; t < 4; ++t) {
                bf16x8 ae = cvt8(er + 32 * (w + 4 * t) + kg * 8);
                #pragma unroll
                for (int nf = 0; nf < 4; ++nf)
                    acc1[nf] = __builtin_amdgcn_mfma_f32_16x16x32_bf16(
                        ae, wg1[t][nf], acc1[nf], 0, 0, 0);
            }
            __builtin_amdgcn_sched_barrier(0);  // keep emb work before the wait
        }

        if (i >= 1) wait64(f1s, (unsigned)i);   // all waves poll independently

        // Shared h1_i fragments (used by G1 slices 16..47 and G2 slices 0..31).
        const __bf16* h1row = h1i + (m0 + l16) * HH;
        bf16x8 ah[8];
        #pragma unroll
        for (int u = 0; u < 8; ++u)
            ah[u] = load_bf8_coh(h1row + 32 * (w + 4 * u) + kg * 8);
        bf16x8 a2[4];
        if (i >= 1) {
            const __bf16* h2row = h2p + (m0 + l16) * EE;
            #pragma unroll
            for (int u = 0; u < 4; ++u)
                a2[u] = load_bf8_coh(h2row + 32 * (w + 4 * u) + kg * 8);
        }

        if (i < SS) {
            #pragma unroll
            for (int u = 0; u < 8; ++u)
                #pragma unroll
                for (int nf = 0; nf < 4; ++nf)
                    acc1[nf] = __builtin_amdgcn_mfma_f32_16x16x32_bf16(
                        ah[u], wg1[u + 4][nf], acc1[nf], 0, 0, 0);
            // D layout: col = lane&15, row = (lane>>4)*4 + reg.
            #pragma unroll
            for (int nf = 0; nf < 4; ++nf)
                #pragma unroll
                for (int q = 0; q < 4; ++q)
                    red[w][kg * 4 + q][nf * 16 + l16] = acc1[nf][q];
        }
        __syncthreads();   // SYNC1

        // WAR lag check before overwriting ring slots (cached, rarely polls).
        if (i >= 8 && (int)f2c < i - 7) {
            do { f2c = min64(f2s); } while ((int)f2c < i - 7);
        }

        if (i < SS) {
            // G1 per-wave epilogue + early f1 signal.
            const f32x4 r0 = *reinterpret_cast<const f32x4*>(&red[0][erow_][c1]);
            const f32x4 r1 = *reinterpret_cast<const f32x4*>(&red[1][erow_][c1]);
            const f32x4 r2 = *reinterpret_cast<const f32x4*>(&red[2][erow_][c1]);
            const f32x4 r3 = *reinterpret_cast<const f32x4*>(&red[3][erow_][c1]);
            f32x4 sv = r0 + r1 + r2 + r3 + bb1;
            float s0 = tanhf(sv[0]), s1 = tanhf(sv[1]);
            float s2 = tanhf(sv[2]), s3 = tanhf(sv[3]);
            st8c(h1n + (m0 + erow_) * HH + n0 + c1, pack4(s0, s1, s2, s3));
            if (i == SS - 1) {
                f32x4 fo = {s0, s1, s2, s3};
                *reinterpret_cast<f32x4*>(h1out + (m0 + erow_) * HH + n0 + c1) = fo;
            }
            wsignal(myf1, (unsigned)(i + 1));
        }

        if (i >= 1) {
            // G2 MFMAs (operands already in registers) — overlaps f1 propagation.
            f32x4 acc2[2] = {{0,0,0,0},{0,0,0,0}};
            #pragma unroll
            for (int u = 0; u < 8; ++u)
                #pragma unroll
                for (int nf = 0; nf < 2; ++nf)
                    acc2[nf] = __builtin_amdgcn_mfma_f32_16x16x32_bf16(
                        ah[u], wg2[u][nf], acc2[nf], 0, 0, 0);
            #pragma unroll
            for (int u = 0; u < 4; ++u)
                #pragma unroll
                for (int nf = 0; nf < 2; ++nf)
                    acc2[nf] = __builtin_amdgcn_mfma_f32_16x16x32_bf16(
                        a2[u], wg2[u + 8][nf], acc2[nf], 0, 0, 0);
            #pragma unroll
            for (int nf = 0; nf < 2; ++nf)
                #pragma unroll
                for (int q = 0; q < 4; ++q)
                    red2[w][kg * 4 + q][nf * 16 + l16] = acc2[nf][q];
        }
        __syncthreads();   // SYNC2
        if (i >= 1) {
            float t0 = red2[0][erow_][c2] + red2[1][erow_][c2] +
                       red2[2][erow_][c2] + red2[3][erow_][c2] + b2a;
            float t1 = red2[0][erow_][c2 + 1] + red2[1][erow_][c2 + 1] +
                       red2[2][erow_][c2 + 1] + red2[3][erow_][c2 + 1] + b2b;
            float s0 = tanhf(t0), s1 = tanhf(t1);
            st4c(h2n + (m0 + erow_) * EE + n20 + c2, pack2(s0, s1));
            if (i == SS) {
                h2out[(m0 + erow_) * EE + n20 + c2] = s0;
                h2out[(m0 + erow_) * EE + n20 + c2 + 1] = s1;
            }
            wsignal(myf2, (unsigned)i);
        }
    }
}

// Fallback per-step kernel (round-1 proven path), if cooperative launch fails.
__global__ __launch_bounds__(256) void step_kernel(
    const int* __restrict__ tok32,
    const float* __restrict__ embW,
    const float* __restrict__ b1, const float* __restrict__ b2,
    const __bf16* __restrict__ W1t, const __bf16* __restrict__ W2t,
    const __bf16* __restrict__ h1cur, __bf16* __restrict__ h1next,
    const __bf16* __restrict__ h2cur, __bf16* __restrict__ h2next,
    float* __restrict__ h1f32, float* __restrict__ h2f32,
    int t, int g1, int g2) {
    const int bid = blockIdx.x;
    const bool is1 = bid < 128;
    if (is1 ? (g1 == 0) : (g2 == 0)) return;
    const int rb = is1 ? bid : (bid - 128);
    const int mi = rb & 3;
    const int ni = rb >> 2;
    const int m0 = mi << 4;
    const int n0 = ni << 5;
    const int N = is1 ? HH : EE;
    const int tid = threadIdx.x;
    const int w = tid >> 6;
    const int l = tid & 63;
    const int l16 = l & 15;
    const int kg = l >> 4;

    __shared__ int tok_s[16];
    __shared__ float red[4][16][33];

    if (is1 && tid < 16) tok_s[tid] = tok32[(m0 + tid) * SS + t];
    __syncthreads();

    const __bf16* Wt = is1 ? W1t : W2t;
    f32x4 acc0 = {0.f, 0.f, 0.f, 0.f};
    f32x4 acc1 = {0.f, 0.f, 0.f, 0.f};
    const int row = m0 + l16;
    const int kb = w * 384;

    #pragma unroll 4
    for (int kk = 0; kk < 384; kk += 32) {
        const int k = kb + kk + kg * 8;
        bf16x8 a;
        if (is1) {
            if (k < EE) a = cvt8(embW + (size_t)tok_s[l16] * EE + k);
            else        a = load_bf8(h1cur + row * HH + (k - EE));
        } else {
            if (k < HH) a = load_bf8(h1cur + row * HH + k);
            else        a = load_bf8(h2cur + row * EE + (k - HH));
        }
        bf16x8 bf0 = load_bf8(Wt + (size_t)(n0 + l16) * KK + k);
        bf16x8 bf1 = load_bf8(Wt + (size_t)(n0 + 16 + l16) * KK + k);
        acc0 = __builtin_amdgcn_mfma_f32_16x16x32_bf16(a, bf0, acc0, 0, 0, 0);
        acc1 = __builtin_amdgcn_mfma_f32_16x16x32_bf16(a, bf1, acc1, 0, 0, 0);
    }

    #pragma unroll
    for (int i = 0; i < 4; ++i) {
        red[w][kg * 4 + i][l16]      = acc0[i];
        red[w][kg * 4 + i][16 + l16] = acc1[i];
    }
    __syncthreads();

    const float* bias = is1 ? b1 : b2;
    for (int c = tid; c < 512; c += 256) {
        int m = c >> 5, n = c & 31;
        float s = red[0][m][n] + red[1][m][n] + red[2][m][n] + red[3][m][n];
        s = tanhf(s + bias[n0 + n]);
        int gi = (m0 + m) * N + (n0 + n);
        if (is1) {
            h1next[gi] = (__bf16)s;
            if (h1f32) h1f32[gi] = s;
        } else {
            h2next[gi] = (__bf16)s;
            if (h2f32) h2f32[gi] = s;
        }
    }
}

// out[64, V] = h2 @ emb_W^T + out_b.
__global__ __launch_bounds__(256) void proj_kernel(
    const __bf16* __restrict__ h2bf,
    const float* __restrict__ embW,
    const float* __restrict__ outb,
    float* __restrict__ out) {
    const int v0 = blockIdx.x << 6;
    const int tid = threadIdx.x;
    const int w = tid >> 6;
    const int l = tid & 63;
    const int l16 = l & 15, kg = l >> 4;
    const int vcol = v0 + w * 16 + l16;
    const int vr = vcol < VV ? vcol : VV - 1;
    f32x4 acc[4] = {{0,0,0,0},{0,0,0,0},{0,0,0,0},{0,0,0,0}};
    #pragma unroll 2
    for (int k0 = 0; k0 < EE; k0 += 32) {
        const int k = k0 + kg * 8;
        bf16x8 bfr = cvt8(embW + (size_t)vr * EE + k);
        #pragma unroll
        for (int mf = 0; mf < 4; ++mf) {
            bf16x8 a = load_bf8(h2bf + (mf * 16 + l16) * EE + k);
            acc[mf] = __builtin_amdgcn_mfma_f32_16x16x32_bf16(a, bfr, acc[mf], 0, 0, 0);
        }
    }
    if (vcol < VV) {
        const float bb = outb[vcol];
        #pragma unroll
        for (int mf = 0; mf < 4; ++mf) {
            #pragma unroll
            for (int i = 0; i < 4; ++i) {
                int b = mf * 16 + kg * 4 + i;
                out[(size_t)b * VV + vcol] = acc[mf][i] + bb;
            }
        }
    }
}

extern "C" void kernel_launch(void* const* d_in, const int* in_sizes, int n_in,
                              void* d_out, int out_size, void* d_ws, size_t ws_size,
                              hipStream_t stream) {
    const void* seq      = d_in[0];
    const float* init_h1 = (const float*)d_in[1];
    const float* init_h2 = (const float*)d_in[2];
    const float* embW    = (const float*)d_in[3];
    const float* W1      = (const float*)d_in[4];
    const float* b1      = (const float*)d_in[5];
    const float* W2      = (const float*)d_in[6];
    const float* b2      = (const float*)d_in[7];
    const float* outb    = (const float*)d_in[8];
    float* out = (float*)d_out;

    char* ws = (char*)d_ws;
    int* tok = (int*)ws;                 ws += (size_t)BB * SS * 4;
    __bf16* W1t = (__bf16*)ws;           ws += (size_t)HH * KK * 2;
    __bf16* W2t = (__bf16*)ws;           ws += (size_t)EE * KK * 2;
    __bf16* h1r = (__bf16*)ws;           ws += (size_t)RING * BB * HH * 2;
    __bf16* h2r = (__bf16*)ws;           ws += (size_t)RING * BB * EE * 2;
    unsigned* bar = (unsigned*)ws;       ws += (size_t)4 * 2 * 64 * PADU * 4;

    hipLaunchKernelGGL(tokens_kernel, dim3(128), dim3(256), 0, stream, seq, tok, bar);
    hipLaunchKernelGGL(transpose_kernel, dim3((KK / 32) * (HH / 32)), dim3(256), 0, stream,
                       W1, W1t, KK, HH);
    hipLaunchKernelGGL(transpose_kernel, dim3((KK / 32) * (EE / 32)), dim3(256), 0, stream,
                       W2, W2t, KK, EE);
    // init states into ring slot 0
    hipLaunchKernelGGL(init_kernel, dim3(256), dim3(256), 0, stream,
                       init_h1, init_h2, h1r, h2r);

    float* h1out = out + (size_t)BB * VV;
    float* h2out = h1out + (size_t)BB * HH;

    const int* tok_c = tok;
    const __bf16* W1t_c = W1t;
    const __bf16* W2t_c = W2t;
    void* args[] = {
        (void*)&tok_c, (void*)&embW, (void*)&b1, (void*)&b2,
        (void*)&W1t_c, (void*)&W2t_c,
        (void*)&h1r, (void*)&h2r,
        (void*)&h1out, (void*)&h2out, (void*)&bar
    };
    hipError_t err = hipLaunchCooperativeKernel((void*)rnn_persist2, dim3(NWG), dim3(256),
                                                args, 0, stream);
    if (err != hipSuccess) {
        // Deterministic fallback: proven per-step path (round 1), ring slots 0/1.
        __bf16* h1bf[2] = {h1r, h1r + (size_t)BB * HH};
        __bf16* h2bf[2] = {h2r, h2r + (size_t)BB * EE};
        for (int t = 0; t <= SS; ++t) {
            int g1 = (t < SS) ? 1 : 0;
            int g2 = (t >= 1) ? 1 : 0;
            const __bf16* h1cur = h1bf[t & 1];
            __bf16* h1next      = h1bf[(t + 1) & 1];
            const __bf16* h2cur = h2bf[(t + 1) & 1];
            __bf16* h2next      = h2bf[t & 1];
            float* h1f = (t == SS - 1) ? h1out : nullptr;
            float* h2f = (t == SS) ? h2out : nullptr;
            hipLaunchKernelGGL(step_kernel, dim3(192), dim3(256), 0, stream,
                               tok, embW, b1, b2, W1t, W2t,
                               h1cur, h1next, h2cur, h2next, h1f, h2f, t, g1, g2);
        }
    }

    // h2_512 lives in ring slot 0 (512 % 8 == 0) on both paths.
    hipLaunchKernelGGL(proj_kernel, dim3((VV + 63) / 64), dim3(256), 0, stream,
                       h2r, embW, outb, out);
}

// Round 7
// 3655.238 us; speedup vs baseline: 1.0015x; 1.0015x over previous
//
#include <hip/hip_runtime.h>
#include <hip/hip_bf16.h>

#define BB 64
#define EE 512
#define HH 1024
#define KK 1536
#define VV 50257
#define SS 512

#define NWG 64     // merged blocks: mi = bid&3 (16 rows), ni = bid>>2 (16 col-tiles)
#define RING 8
#define PADU 32    // unsigned per flag slot = 128 B line

typedef __bf16 bf16x8 __attribute__((ext_vector_type(8)));
typedef float f32x4 __attribute__((ext_vector_type(4)));

__device__ __forceinline__ bf16x8 load_bf8(const __bf16* p) {
    return *reinterpret_cast<const bf16x8*>(p);
}

__device__ __forceinline__ bf16x8 cvt8(const float* p) {
    f32x4 a = *reinterpret_cast<const f32x4*>(p);
    f32x4 b = *reinterpret_cast<const f32x4*>(p + 4);
    bf16x8 r;
    r[0] = (__bf16)a[0]; r[1] = (__bf16)a[1]; r[2] = (__bf16)a[2]; r[3] = (__bf16)a[3];
    r[4] = (__bf16)b[0]; r[5] = (__bf16)b[1]; r[6] = (__bf16)b[2]; r[7] = (__bf16)b[3];
    return r;
}

// 16B coherent (system-scope, cache-bypassing) load/store. We don't need
// 16B atomicity — only (a) stores that reach the coherence point before the
// vmcnt(0)-ordered flag, (b) loads served from the coherence point. sc0 sc1
// gives both; 16B granularity halves fabric transactions vs 8B atomics.
__device__ __forceinline__ void st16c(void* p, f32x4 v) {
    asm volatile("global_store_dwordx4 %0, %1, off sc0 sc1" :: "v"(p), "v"(v) : "memory");
}
__device__ __forceinline__ f32x4 ld16c(const void* p) {
    f32x4 r;
    asm volatile("global_load_dwordx4 %0, %1, off sc0 sc1" : "=v"(r) : "v"(p) : "memory");
    return r;
}
union cvu { f32x4 f; bf16x8 h8; __bf16 h[8]; };

// Wave-0 polls all 64 per-wave flag slots; barrier releases the block.
__device__ __forceinline__ void block_wait(const unsigned* slots, unsigned target) {
    if (threadIdx.x < 64) {
        const int l = threadIdx.x;
        for (;;) {
            unsigned v = __hip_atomic_load(&slots[l * PADU], __ATOMIC_RELAXED,
                                           __HIP_MEMORY_SCOPE_AGENT);
            if (__all((int)(v >= target))) break;
            __builtin_amdgcn_s_sleep(1);   // backoff: cut fabric poll pressure
        }
    }
    __syncthreads();
    asm volatile("" ::: "memory");
}

// Wave-parallel min over the 64 slots (broadcast to all lanes).
__device__ __forceinline__ unsigned min64(const unsigned* slots) {
    const int l = threadIdx.x & 63;
    unsigned v = __hip_atomic_load(&slots[l * PADU], __ATOMIC_RELAXED,
                                   __HIP_MEMORY_SCOPE_AGENT);
    #pragma unroll
    for (int o = 32; o; o >>= 1) {
        unsigned u = (unsigned)__shfl_xor((int)v, o, 64);
        v = u < v ? u : v;
    }
    return v;
}

// Per-wave publish: this wave's coherent stores acked, then flag store.
__device__ __forceinline__ void wsignal(unsigned* slot, unsigned val) {
    asm volatile("s_waitcnt vmcnt(0)" ::: "memory");
    if ((threadIdx.x & 63) == 0)
        __hip_atomic_store(slot, val, __ATOMIC_RELAXED, __HIP_MEMORY_SCOPE_AGENT);
}

// Decode tokens to int32 (auto-detect int64 vs int32) + zero the flag slots.
__global__ void tokens_kernel(const void* __restrict__ seq, int* __restrict__ tok,
                              unsigned* __restrict__ bar) {
    int z = blockIdx.x * 256 + threadIdx.x;
    if (z < 4 * 2 * 64 * PADU)
        __hip_atomic_store(&bar[z], 0u, __ATOMIC_RELAXED, __HIP_MEMORY_SCOPE_AGENT);
    const unsigned* u = (const unsigned*)seq;
    bool is64 = true;
    #pragma unroll 1
    for (int i = 0; i < 64; ++i) {
        if (u[2 * i + 1] != 0u) { is64 = false; break; }
    }
    int i = blockIdx.x * 256 + threadIdx.x;
    if (i < BB * SS) tok[i] = is64 ? (int)u[2 * i] : (int)u[i];
}

// fp32 [R][C] row-major -> bf16 [C][R]
__global__ __launch_bounds__(256) void transpose_kernel(
    const float* __restrict__ in, __bf16* __restrict__ out, int R, int C) {
    __shared__ float t[32][33];
    int bc = C >> 5;
    int br = blockIdx.x / bc;
    int bco = blockIdx.x % bc;
    int R0 = br << 5, C0 = bco << 5;
    int c = threadIdx.x & 31, r0 = threadIdx.x >> 5;
    #pragma unroll
    for (int i = 0; i < 4; ++i) {
        int r = r0 + i * 8;
        t[r][c] = in[(size_t)(R0 + r) * C + C0 + c];
    }
    __syncthreads();
    #pragma unroll
    for (int i = 0; i < 4; ++i) {
        int r = r0 + i * 8;
        out[(size_t)(C0 + r) * R + R0 + c] = (__bf16)t[c][r];
    }
}

__global__ void init_kernel(const float* __restrict__ h1, const float* __restrict__ h2,
                            __bf16* __restrict__ h1bf, __bf16* __restrict__ h2bf) {
    int i = blockIdx.x * 256 + threadIdx.x;
    if (i < BB * HH) h1bf[i] = (__bf16)h1[i];
    if (i < BB * EE) h2bf[i] = (__bf16)h2[i];
}

// Persistent merged-role recurrence, split waits:
//   wait f1>=i   -> gates h1_i reads (G1 tail-part + G2 h1-part)
//   wait f2>=i-1 -> gates h2_{i-1} reads (FIX of round-6 race: early f1
//                   signal does NOT imply remote G2@i-1 epilogues are done)
// Per-wave f1 signal fires right after that wave's h1 rows drain, BEFORE the
// G2 tail -> consumers' G1 chains start early; G2 runs in their shadow.
// Ring depth 8; WAR covered by cached lag check f2min >= i-7.
__global__ __launch_bounds__(256, 1) void rnn_persist2(
    const int* __restrict__ tok32, const float* __restrict__ embW,
    const float* __restrict__ b1, const float* __restrict__ b2,
    const __bf16* __restrict__ W1t, const __bf16* __restrict__ W2t,
    __bf16* __restrict__ h1r, __bf16* __restrict__ h2r,
    float* __restrict__ h1out, float* __restrict__ h2out,
    unsigned* __restrict__ bar) {
    const int bid = blockIdx.x;
    const int mi = bid & 3;
    const int ni = bid >> 2;
    const int m0 = mi << 4;
    const int n0 = ni << 6;      // G1 column tile
    const int n20 = ni << 5;     // G2 column tile
    const int tid = threadIdx.x;
    const int w = tid >> 6;
    const int l = tid & 63;
    const int l16 = l & 15;
    const int kg = l >> 4;
    unsigned* f1s = bar + mi * (2 * 64 * PADU);
    unsigned* f2s = f1s + 64 * PADU;
    unsigned* myf1 = &f1s[(ni * 4 + w) * PADU];
    unsigned* myf2 = &f2s[(ni * 4 + w) * PADU];

    __shared__ int tok_s[SS][16];
    __shared__ float red[4][16][68];    // rows 272B: 16B-aligned at 8-col offsets
    __shared__ float red2[4][16][36];   // rows 144B: 16B-aligned

    for (int idx = tid; idx < SS * 16; idx += 256) {
        int t = idx >> 4, r = idx & 15;
        tok_s[t][r] = tok32[(m0 + r) * SS + t];
    }

    // Register-resident weights: wave w holds K-slices {w+4t, t=0..11}.
    bf16x8 wg1[12][4];
    bf16x8 wg2[12][2];
    #pragma unroll
    for (int t = 0; t < 12; ++t) {
        const int kb = 32 * (w + 4 * t) + kg * 8;
        #pragma unroll
        for (int nf = 0; nf < 4; ++nf)
            wg1[t][nf] = load_bf8(W1t + (size_t)(n0 + nf * 16 + l16) * KK + kb);
        #pragma unroll
        for (int nf = 0; nf < 2; ++nf)
            wg2[t][nf] = load_bf8(W2t + (size_t)(n20 + nf * 16 + l16) * KK + kb);
    }
    {   // Pin in the register file (round-3 lesson).
        f32x4* p1 = reinterpret_cast<f32x4*>(&wg1[0][0]);
        #pragma unroll
        for (int q = 0; q < 48; ++q) asm volatile("" : "+v"(p1[q]));
        f32x4* p2 = reinterpret_cast<f32x4*>(&wg2[0][0]);
        #pragma unroll
        for (int q = 0; q < 24; ++q) asm volatile("" : "+v"(p2[q]));
    }

    // Epilogue mappings (8 cols/lane -> one 16B store):
    // G1: lanes<32: row = 4w + (l>>3), cols c1 = (l&7)*8.
    // G2: lanes<16: row = 4w + (l>>2), cols c2 = (l&3)*8.
    const int r1 = 4 * w + ((l & 31) >> 3);
    const int c1 = (l & 7) * 8;
    const int r2 = 4 * w + ((l & 15) >> 2);
    const int c2 = (l & 3) * 8;
    const f32x4 b1lo = *reinterpret_cast<const f32x4*>(b1 + n0 + c1);
    const f32x4 b1hi = *reinterpret_cast<const f32x4*>(b1 + n0 + c1 + 4);
    const f32x4 b2lo = *reinterpret_cast<const f32x4*>(b2 + n20 + c2);
    const f32x4 b2hi = *reinterpret_cast<const f32x4*>(b2 + n20 + c2 + 4);

    unsigned f2c = 0;  // cached min of f2 flags

    __syncthreads();

    for (int i = 0; i <= SS; ++i) {
        const __bf16* h1i = h1r + (size_t)(i & 7) * BB * HH;        // h1_i
        __bf16*       h1n = h1r + (size_t)((i + 1) & 7) * BB * HH;  // h1_{i+1}
        const __bf16* h2p = h2r + (size_t)((i + 7) & 7) * BB * EE;  // h2_{i-1}
        __bf16*       h2n = h2r + (size_t)(i & 7) * BB * EE;        // h2_i

        f32x4 acc1[4] = {{0,0,0,0},{0,0,0,0},{0,0,0,0},{0,0,0,0}};
        if (i < SS) {
            // Pre-wait: embedding-part MFMAs (cached path).
            const float* er = embW + (size_t)tok_s[i][l16] * EE;
            #pragma unroll
            for (int t = 0; t < 4; ++t) {
                bf16x8 ae = cvt8(er + 32 * (w + 4 * t) + kg * 8);
                #pragma unroll
                for (int nf = 0; nf < 4; ++nf)
                    acc1[nf] = __builtin_amdgcn_mfma_f32_16x16x32_bf16(
                        ae, wg1[t][nf], acc1[nf], 0, 0, 0);
            }
            __builtin_amdgcn_sched_barrier(0);
        }

        if (i >= 1) block_wait(f1s, (unsigned)i);   // gates h1_i

        // Shared h1_i fragments (G1 slices 16..47 == G2 slices 0..31).
        const __bf16* h1row = h1i + (m0 + l16) * HH;
        bf16x8 ah[8];
        #pragma unroll
        for (int u = 0; u < 8; ++u) {
            cvu t; t.f = ld16c(h1row + 32 * (w + 4 * u) + kg * 8);
            ah[u] = t.h8;
        }
        asm volatile("s_waitcnt vmcnt(0)" ::: "memory");
        __builtin_amdgcn_sched_barrier(0);

        if (i < SS) {
            #pragma unroll
            for (int u = 0; u < 8; ++u)
                #pragma unroll
                for (int nf = 0; nf < 4; ++nf)
                    acc1[nf] = __builtin_amdgcn_mfma_f32_16x16x32_bf16(
                        ah[u], wg1[u + 4][nf], acc1[nf], 0, 0, 0);
            // D layout: col = lane&15, row = (lane>>4)*4 + reg.
            #pragma unroll
            for (int nf = 0; nf < 4; ++nf)
                #pragma unroll
                for (int q = 0; q < 4; ++q)
                    red[w][kg * 4 + q][nf * 16 + l16] = acc1[nf][q];
        }
        __syncthreads();   // SYNC1

        // Ring WAR lag check before overwriting slot i+1 / i (cached).
        if (i >= 8 && (int)f2c < i - 7) {
            do { f2c = min64(f2s); } while ((int)f2c < i - 7);
        }

        if (i < SS) {
            // G1 per-wave epilogue (lanes<32) + early per-wave f1 signal.
            if ((l & 63) < 32) {
                f32x4 lo = b1lo, hi = b1hi;
                #pragma unroll
                for (int p = 0; p < 4; ++p) {
                    lo += *reinterpret_cast<const f32x4*>(&red[p][r1][c1]);
                    hi += *reinterpret_cast<const f32x4*>(&red[p][r1][c1 + 4]);
                }
                cvu o;
                #pragma unroll
                for (int j = 0; j < 4; ++j) {
                    o.h[j]     = (__bf16)tanhf(lo[j]);
                    o.h[j + 4] = (__bf16)tanhf(hi[j]);
                }
                st16c(h1n + (m0 + r1) * HH + n0 + c1, o.f);
                if (i == SS - 1) {
                    float* op = h1out + (m0 + r1) * HH + n0 + c1;
                    #pragma unroll
                    for (int j = 0; j < 8; ++j)
                        op[j] = __bfloat162float(((__hip_bfloat16*)&o.h[j])[0]);
                }
            }
            wsignal(myf1, (unsigned)(i + 1));
        }

        if (i >= 1) {
            // RACE FIX: h2_{i-1} reads require remote G2@i-1 done.
            block_wait(f2s, (unsigned)(i - 1));
            const __bf16* h2row = h2p + (m0 + l16) * EE;
            bf16x8 a2[4];
            #pragma unroll
            for (int u = 0; u < 4; ++u) {
                cvu t; t.f = ld16c(h2row + 32 * (w + 4 * u) + kg * 8);
                a2[u] = t.h8;
            }
            asm volatile("s_waitcnt vmcnt(0)" ::: "memory");
            __builtin_amdgcn_sched_barrier(0);

            f32x4 acc2[2] = {{0,0,0,0},{0,0,0,0}};
            #pragma unroll
            for (int u = 0; u < 8; ++u)
                #pragma unroll
                for (int nf = 0; nf < 2; ++nf)
                    acc2[nf] = __builtin_amdgcn_mfma_f32_16x16x32_bf16(
                        ah[u], wg2[u][nf], acc2[nf], 0, 0, 0);
            #pragma unroll
            for (int u = 0; u < 4; ++u)
                #pragma unroll
                for (int nf = 0; nf < 2; ++nf)
                    acc2[nf] = __builtin_amdgcn_mfma_f32_16x16x32_bf16(
                        a2[u], wg2[u + 8][nf], acc2[nf], 0, 0, 0);
            #pragma unroll
            for (int nf = 0; nf < 2; ++nf)
                #pragma unroll
                for (int q = 0; q < 4; ++q)
                    red2[w][kg * 4 + q][nf * 16 + l16] = acc2[nf][q];
            __syncthreads();   // SYNC2
            if ((l & 63) < 16) {
                f32x4 lo = b2lo, hi = b2hi;
                #pragma unroll
                for (int p = 0; p < 4; ++p) {
                    lo += *reinterpret_cast<const f32x4*>(&red2[p][r2][c2]);
                    hi += *reinterpret_cast<const f32x4*>(&red2[p][r2][c2 + 4]);
                }
                cvu o;
                #pragma unroll
                for (int j = 0; j < 4; ++j) {
                    o.h[j]     = (__bf16)tanhf(lo[j]);
                    o.h[j + 4] = (__bf16)tanhf(hi[j]);
                }
                st16c(h2n + (m0 + r2) * EE + n20 + c2, o.f);
                if (i == SS) {
                    float* op = h2out + (m0 + r2) * EE + n20 + c2;
                    #pragma unroll
                    for (int j = 0; j < 8; ++j)
                        op[j] = __bfloat162float(((__hip_bfloat16*)&o.h[j])[0]);
                }
            }
            wsignal(myf2, (unsigned)i);
        }
    }
}

// Fallback per-step kernel (round-1 proven path), if cooperative launch fails.
__global__ __launch_bounds__(256) void step_kernel(
    const int* __restrict__ tok32,
    const float* __restrict__ embW,
    const float* __restrict__ b1, const float* __restrict__ b2,
    const __bf16* __restrict__ W1t, const __bf16* __restrict__ W2t,
    const __bf16* __restrict__ h1cur, __bf16* __restrict__ h1next,
    const __bf16* __restrict__ h2cur, __bf16* __restrict__ h2next,
    float* __restrict__ h1f32, float* __restrict__ h2f32,
    int t, int g1, int g2) {
    const int bid = blockIdx.x;
    const bool is1 = bid < 128;
    if (is1 ? (g1 == 0) : (g2 == 0)) return;
    const int rb = is1 ? bid : (bid - 128);
    const int mi = rb & 3;
    const int ni = rb >> 2;
    const int m0 = mi << 4;
    const int n0 = ni << 5;
    const int N = is1 ? HH : EE;
    const int tid = threadIdx.x;
    const int w = tid >> 6;
    const int l = tid & 63;
    const int l16 = l & 15;
    const int kg = l >> 4;

    __shared__ int tok_s[16];
    __shared__ float red[4][16][33];

    if (is1 && tid < 16) tok_s[tid] = tok32[(m0 + tid) * SS + t];
    __syncthreads();

    const __bf16* Wt = is1 ? W1t : W2t;
    f32x4 acc0 = {0.f, 0.f, 0.f, 0.f};
    f32x4 acc1 = {0.f, 0.f, 0.f, 0.f};
    const int row = m0 + l16;
    const int kb = w * 384;

    #pragma unroll 4
    for (int kk = 0; kk < 384; kk += 32) {
        const int k = kb + kk + kg * 8;
        bf16x8 a;
        if (is1) {
            if (k < EE) a = cvt8(embW + (size_t)tok_s[l16] * EE + k);
            else        a = load_bf8(h1cur + row * HH + (k - EE));
        } else {
            if (k < HH) a = load_bf8(h1cur + row * HH + k);
            else        a = load_bf8(h2cur + row * EE + (k - HH));
        }
        bf16x8 bf0 = load_bf8(Wt + (size_t)(n0 + l16) * KK + k);
        bf16x8 bf1 = load_bf8(Wt + (size_t)(n0 + 16 + l16) * KK + k);
        acc0 = __builtin_amdgcn_mfma_f32_16x16x32_bf16(a, bf0, acc0, 0, 0, 0);
        acc1 = __builtin_amdgcn_mfma_f32_16x16x32_bf16(a, bf1, acc1, 0, 0, 0);
    }

    #pragma unroll
    for (int i = 0; i < 4; ++i) {
        red[w][kg * 4 + i][l16]      = acc0[i];
        red[w][kg * 4 + i][16 + l16] = acc1[i];
    }
    __syncthreads();

    const float* bias = is1 ? b1 : b2;
    for (int c = tid; c < 512; c += 256) {
        int m = c >> 5, n = c & 31;
        float s = red[0][m][n] + red[1][m][n] + red[2][m][n] + red[3][m][n];
        s = tanhf(s + bias[n0 + n]);
        int gi = (m0 + m) * N + (n0 + n);
        if (is1) {
            h1next[gi] = (__bf16)s;
            if (h1f32) h1f32[gi] = s;
        } else {
            h2next[gi] = (__bf16)s;
            if (h2f32) h2f32[gi] = s;
        }
    }
}

// out[64, V] = h2 @ emb_W^T + out_b.
__global__ __launch_bounds__(256) void proj_kernel(
    const __bf16* __restrict__ h2bf,
    const float* __restrict__ embW,
    const float* __restrict__ outb,
    float* __restrict__ out) {
    const int v0 = blockIdx.x << 6;
    const int tid = threadIdx.x;
    const int w = tid >> 6;
    const int l = tid & 63;
    const int l16 = l & 15, kg = l >> 4;
    const int vcol = v0 + w * 16 + l16;
    const int vr = vcol < VV ? vcol : VV - 1;
    f32x4 acc[4] = {{0,0,0,0},{0,0,0,0},{0,0,0,0},{0,0,0,0}};
    #pragma unroll 2
    for (int k0 = 0; k0 < EE; k0 += 32) {
        const int k = k0 + kg * 8;
        bf16x8 bfr = cvt8(embW + (size_t)vr * EE + k);
        #pragma unroll
        for (int mf = 0; mf < 4; ++mf) {
            bf16x8 a = load_bf8(h2bf + (mf * 16 + l16) * EE + k);
            acc[mf] = __builtin_amdgcn_mfma_f32_16x16x32_bf16(a, bfr, acc[mf], 0, 0, 0);
        }
    }
    if (vcol < VV) {
        const float bb = outb[vcol];
        #pragma unroll
        for (int mf = 0; mf < 4; ++mf) {
            #pragma unroll
            for (int i = 0; i < 4; ++i) {
                int b = mf * 16 + kg * 4 + i;
                out[(size_t)b * VV + vcol] = acc[mf][i] + bb;
            }
        }
    }
}

extern "C" void kernel_launch(void* const* d_in, const int* in_sizes, int n_in,
                              void* d_out, int out_size, void* d_ws, size_t ws_size,
                              hipStream_t stream) {
    const void* seq      = d_in[0];
    const float* init_h1 = (const float*)d_in[1];
    const float* init_h2 = (const float*)d_in[2];
    const float* embW    = (const float*)d_in[3];
    const float* W1      = (const float*)d_in[4];
    const float* b1      = (const float*)d_in[5];
    const float* W2      = (const float*)d_in[6];
    const float* b2      = (const float*)d_in[7];
    const float* outb    = (const float*)d_in[8];
    float* out = (float*)d_out;

    char* ws = (char*)d_ws;
    int* tok = (int*)ws;                 ws += (size_t)BB * SS * 4;
    __bf16* W1t = (__bf16*)ws;           ws += (size_t)HH * KK * 2;
    __bf16* W2t = (__bf16*)ws;           ws += (size_t)EE * KK * 2;
    __bf16* h1r = (__bf16*)ws;           ws += (size_t)RING * BB * HH * 2;
    __bf16* h2r = (__bf16*)ws;           ws += (size_t)RING * BB * EE * 2;
    unsigned* bar = (unsigned*)ws;       ws += (size_t)4 * 2 * 64 * PADU * 4;

    hipLaunchKernelGGL(tokens_kernel, dim3(128), dim3(256), 0, stream, seq, tok, bar);
    hipLaunchKernelGGL(transpose_kernel, dim3((KK / 32) * (HH / 32)), dim3(256), 0, stream,
                       W1, W1t, KK, HH);
    hipLaunchKernelGGL(transpose_kernel, dim3((KK / 32) * (EE / 32)), dim3(256), 0, stream,
                       W2, W2t, KK, EE);
    // init states into ring slot 0
    hipLaunchKernelGGL(init_kernel, dim3(256), dim3(256), 0, stream,
                       init_h1, init_h2, h1r, h2r);

    float* h1out = out + (size_t)BB * VV;
    float* h2out = h1out + (size_t)BB * HH;

    const int* tok_c = tok;
    const __bf16* W1t_c = W1t;
    const __bf16* W2t_c = W2t;
    void* args[] = {
        (void*)&tok_c, (void*)&embW, (void*)&b1, (void*)&b2,
        (void*)&W1t_c, (void*)&W2t_c,
        (void*)&h1r, (void*)&h2r,
        (void*)&h1out, (void*)&h2out, (void*)&bar
    };
    hipError_t err = hipLaunchCooperativeKernel((void*)rnn_persist2, dim3(NWG), dim3(256),
                                                args, 0, stream);
    if (err != hipSuccess) {
        // Deterministic fallback: proven per-step path (round 1), ring slots 0/1.
        __bf16* h1bf[2] = {h1r, h1r + (size_t)BB * HH};
        __bf16* h2bf[2] = {h2r, h2r + (size_t)BB * EE};
        for (int t = 0; t <= SS; ++t) {
            int g1 = (t < SS) ? 1 : 0;
            int g2 = (t >= 1) ? 1 : 0;
            const __bf16* h1cur = h1bf[t & 1];
            __bf16* h1next      = h1bf[(t + 1) & 1];
            const __bf16* h2cur = h2bf[(t + 1) & 1];
            __bf16* h2next      = h2bf[t & 1];
            float* h1f = (t == SS - 1) ? h1out : nullptr;
            float* h2f = (t == SS) ? h2out : nullptr;
            hipLaunchKernelGGL(step_kernel, dim3(192), dim3(256), 0, stream,
                               tok, embW, b1, b2, W1t, W2t,
                               h1cur, h1next, h2cur, h2next, h1f, h2f, t, g1, g2);
        }
    }

    // h2_512 lives in ring slot 0 (512 % 8 == 0) on both paths.
    hipLaunchKernelGGL(proj_kernel, dim3((VV + 63) / 64), dim3(256), 0, stream,
                       h2r, embW, outb, out);
}

// Round 8
// 2119.509 us; speedup vs baseline: 1.7272x; 1.7246x over previous
//
#include <hip/hip_runtime.h>
#include <hip/hip_bf16.h>

#define BB 64
#define EE 512
#define HH 1024
#define KK 1536
#define VV 50257
#define SS 512

#define NWG1 64    // G1 blocks: mi=bid&3 (16 rows), ni=bid>>2 (16 x 64-col tiles)
#define NWG2 32    // G2 blocks: mi=rb&3,  ni=rb>>2 (8 x 64-col tiles)
#define NWG (NWG1 + NWG2)
#define RING 8
#define PADU 32    // unsigned per flag slot = 128 B line

typedef __bf16 bf16x8 __attribute__((ext_vector_type(8)));
typedef float f32x4 __attribute__((ext_vector_type(4)));

__device__ __forceinline__ bf16x8 load_bf8(const __bf16* p) {
    return *reinterpret_cast<const bf16x8*>(p);
}

__device__ __forceinline__ bf16x8 cvt8(const float* p) {
    f32x4 a = *reinterpret_cast<const f32x4*>(p);
    f32x4 b = *reinterpret_cast<const f32x4*>(p + 4);
    bf16x8 r;
    r[0] = (__bf16)a[0]; r[1] = (__bf16)a[1]; r[2] = (__bf16)a[2]; r[3] = (__bf16)a[3];
    r[4] = (__bf16)b[0]; r[5] = (__bf16)b[1]; r[6] = (__bf16)b[2]; r[7] = (__bf16)b[3];
    return r;
}

// 16B coherent load/store (validated in round 7: sc0 sc1 routes past the
// per-XCD caches; store-acks retire vmcnt at the coherence point).
__device__ __forceinline__ void st16c(void* p, f32x4 v) {
    asm volatile("global_store_dwordx4 %0, %1, off sc0 sc1" :: "v"(p), "v"(v) : "memory");
}
__device__ __forceinline__ f32x4 ld16c(const void* p) {
    f32x4 r;
    asm volatile("global_load_dwordx4 %0, %1, off sc0 sc1" : "=v"(r) : "v"(p) : "memory");
    return r;
}
union cvu { f32x4 f; bf16x8 h8; __bf16 h[8]; };

// Per-wave wait (no block barrier): 64 lanes poll nslots flag lines.
__device__ __forceinline__ void wwait(const unsigned* slots, int nslots, unsigned target) {
    const int l = threadIdx.x & 63;
    const int idx = l < nslots ? l : 0;
    for (;;) {
        unsigned v = __hip_atomic_load(&slots[idx * PADU], __ATOMIC_RELAXED,
                                       __HIP_MEMORY_SCOPE_AGENT);
        if (l >= nslots) v = target;
        if (__all((int)(v >= target))) break;
        __builtin_amdgcn_s_sleep(1);
    }
    asm volatile("" ::: "memory");
}

// Wave-parallel min over nslots flag slots (broadcast to all lanes).
__device__ __forceinline__ unsigned minpoll(const unsigned* slots, int nslots) {
    const int l = threadIdx.x & 63;
    unsigned v = 0xFFFFFFFFu;
    if (l < nslots)
        v = __hip_atomic_load(&slots[l * PADU], __ATOMIC_RELAXED,
                              __HIP_MEMORY_SCOPE_AGENT);
    #pragma unroll
    for (int o = 32; o; o >>= 1) {
        unsigned u = (unsigned)__shfl_xor((int)v, o, 64);
        v = u < v ? u : v;
    }
    return v;
}

// Per-wave publish: this wave's coherent stores acked, then flag store.
__device__ __forceinline__ void wsignal(unsigned* slot, unsigned val) {
    asm volatile("s_waitcnt vmcnt(0)" ::: "memory");
    if ((threadIdx.x & 63) == 0)
        __hip_atomic_store(slot, val, __ATOMIC_RELAXED, __HIP_MEMORY_SCOPE_AGENT);
}

// Fast tanh via v_exp; rel err ~1e-6 << bf16 storage quantization.
__device__ __forceinline__ float ftanh(float x) {
    float ax = fabsf(x);
    float e = __expf(-2.0f * ax);
    float r = (1.0f - e) / (1.0f + e);
    return x < 0.0f ? -r : r;
}

// Decode tokens to int32 (auto-detect int64 vs int32) + zero the flag slots.
__global__ void tokens_kernel(const void* __restrict__ seq, int* __restrict__ tok,
                              unsigned* __restrict__ bar) {
    int z = blockIdx.x * 256 + threadIdx.x;
    if (z < 4 * 96 * PADU)
        __hip_atomic_store(&bar[z], 0u, __ATOMIC_RELAXED, __HIP_MEMORY_SCOPE_AGENT);
    const unsigned* u = (const unsigned*)seq;
    bool is64 = true;
    #pragma unroll 1
    for (int i = 0; i < 64; ++i) {
        if (u[2 * i + 1] != 0u) { is64 = false; break; }
    }
    int i = blockIdx.x * 256 + threadIdx.x;
    if (i < BB * SS) tok[i] = is64 ? (int)u[2 * i] : (int)u[i];
}

// fp32 [R][C] row-major -> bf16 [C][R]
__global__ __launch_bounds__(256) void transpose_kernel(
    const float* __restrict__ in, __bf16* __restrict__ out, int R, int C) {
    __shared__ float t[32][33];
    int bc = C >> 5;
    int br = blockIdx.x / bc;
    int bco = blockIdx.x % bc;
    int R0 = br << 5, C0 = bco << 5;
    int c = threadIdx.x & 31, r0 = threadIdx.x >> 5;
    #pragma unroll
    for (int i = 0; i < 4; ++i) {
        int r = r0 + i * 8;
        t[r][c] = in[(size_t)(R0 + r) * C + C0 + c];
    }
    __syncthreads();
    #pragma unroll
    for (int i = 0; i < 4; ++i) {
        int r = r0 + i * 8;
        out[(size_t)(C0 + r) * R + R0 + c] = (__bf16)t[c][r];
    }
}

__global__ void init_kernel(const float* __restrict__ h1, const float* __restrict__ h2,
                            __bf16* __restrict__ h1bf, __bf16* __restrict__ h2bf) {
    int i = blockIdx.x * 256 + threadIdx.x;
    if (i < BB * HH) h1bf[i] = (__bf16)h1[i];
    if (i < BB * EE) h2bf[i] = (__bf16)h2[i];
}

// Persistent DECOUPLED-chain recurrence.
// G1 blocks run the h1 chain alone (h1_{t+1} = tanh([e_t, h1_t] W1)): one
// flag hop per step, no f2 wait (only an amortized depth-8 ring-WAR check).
// G2 blocks trail, computing h2_t = tanh([h1_t, h2_{t-1}] W2): their f1 wait
// is instant (h1_t long published); their own f2 hop runs concurrently with
// G1's next step -> system period = max(chain periods), not the sum.
// Ring WAR proofs:
//  h1 slot (i+1)&7 overwrite at G1@i: G1 readers all at step >= i (f1
//  lockstep); G2 readers of h1_{i-7} gated done by f2min >= i-7 (checked).
//  G2@j reading h1_j (slot j&7): overwritten only by G1@j+7 which needs
//  f2min >= j, i.e. this very read completed. Exactly tight.
//  h2 slot j&7 overwrite at G2@j: all G2 at step >= j-1 via f2 wait; depth-8
//  trivially covers. All data/flags via validated sc0sc1 / agent-relaxed ops.
__global__ __launch_bounds__(256, 1) void rnn_persist3(
    const int* __restrict__ tok32, const float* __restrict__ embW,
    const float* __restrict__ b1, const float* __restrict__ b2,
    const __bf16* __restrict__ W1t, const __bf16* __restrict__ W2t,
    __bf16* __restrict__ h1r, __bf16* __restrict__ h2r,
    float* __restrict__ h1out, float* __restrict__ h2out,
    unsigned* __restrict__ bar) {
    const int bid = blockIdx.x;
    const bool g1 = bid < NWG1;
    const int rb = g1 ? bid : bid - NWG1;
    const int mi = rb & 3;
    const int ni = rb >> 2;          // 0..15 (G1) / 0..7 (G2)
    const int m0 = mi << 4;
    const int n0 = ni << 6;          // 64-col tile for both roles
    const int tid = threadIdx.x;
    const int w = tid >> 6;
    const int l = tid & 63;
    const int l16 = l & 15;
    const int kg = l >> 4;
    unsigned* f1s = bar + mi * (96 * PADU);   // 64 G1-wave slots per mi
    unsigned* f2s = f1s + 64 * PADU;          // 32 G2-wave slots per mi
    unsigned* myf = g1 ? &f1s[(ni * 4 + w) * PADU] : &f2s[(ni * 4 + w) * PADU];

    __shared__ int tok_s[SS][16];
    __shared__ float red[2][4][16][68];   // double-buffered cross-wave reduce

    if (g1) {
        for (int idx = tid; idx < SS * 16; idx += 256) {
            int t = idx >> 4, r = idx & 15;
            tok_s[t][r] = tok32[(m0 + r) * SS + t];
        }
    }

    // Register-resident weights: wave w holds K-slices {w+4t, t=0..11} of a
    // 64-col panel. G1 panel from W1t; G2 panel from W2t. 48 frags = 192 regs.
    const __bf16* Wt = g1 ? W1t : W2t;
    bf16x8 wreg[12][4];
    #pragma unroll
    for (int t = 0; t < 12; ++t) {
        const int kb = 32 * (w + 4 * t) + kg * 8;
        #pragma unroll
        for (int nf = 0; nf < 4; ++nf)
            wreg[t][nf] = load_bf8(Wt + (size_t)(n0 + nf * 16 + l16) * KK + kb);
    }
    {   // Pin in the register file (round-3 lesson: else re-fetched per step).
        f32x4* p1 = reinterpret_cast<f32x4*>(&wreg[0][0]);
        #pragma unroll
        for (int q = 0; q < 48; ++q) asm volatile("" : "+v"(p1[q]));
    }

    // Epilogue mapping (lanes<32): row = 4w + (l>>3), cols c1 = (l&7)*8.
    const int r1 = 4 * w + ((l & 31) >> 3);
    const int c1 = (l & 7) * 8;
    const float* bias = g1 ? b1 : b2;
    const f32x4 blo = *reinterpret_cast<const f32x4*>(bias + n0 + c1);
    const f32x4 bhi = *reinterpret_cast<const f32x4*>(bias + n0 + c1 + 4);

    unsigned f2c = 0;  // G1's cached min of f2 flags (ring-WAR)

    __syncthreads();

    if (g1) {
        // ---------------- h1 chain ----------------
        for (int i = 0; i < SS; ++i) {
            const __bf16* h1i = h1r + (size_t)(i & 7) * BB * HH;
            __bf16*       h1n = h1r + (size_t)((i + 1) & 7) * BB * HH;

            // Pre-wait: embedding-part MFMAs (slices w+4t, t<4 -> k<512).
            f32x4 acc[4] = {{0,0,0,0},{0,0,0,0},{0,0,0,0},{0,0,0,0}};
            const float* er = embW + (size_t)tok_s[i][l16] * EE;
            #pragma unroll
            for (int t = 0; t < 4; ++t) {
                bf16x8 ae = cvt8(er + 32 * (w + 4 * t) + kg * 8);
                #pragma unroll
                for (int nf = 0; nf < 4; ++nf)
                    acc[nf] = __builtin_amdgcn_mfma_f32_16x16x32_bf16(
                        ae, wreg[t][nf], acc[nf], 0, 0, 0);
            }
            __builtin_amdgcn_sched_barrier(0);

            // Amortized ring-WAR check (off critical path, before the wait):
            // slot (i+1)&7 holds h1_{i-7}; G2 must have consumed it.
            if (i >= 7 && (int)f2c < i - 7) {
                do { f2c = minpoll(f2s, 32); } while ((int)f2c < i - 7);
            }

            if (i) wwait(f1s, 64, (unsigned)i);   // the ONE hop per step

            const __bf16* h1row = h1i + (m0 + l16) * HH;
            bf16x8 ah[8];
            #pragma unroll
            for (int u = 0; u < 8; ++u) {
                cvu t_; t_.f = ld16c(h1row + 32 * (w + 4 * u) + kg * 8);
                ah[u] = t_.h8;
            }
            asm volatile("s_waitcnt vmcnt(0)" ::: "memory");
            __builtin_amdgcn_sched_barrier(0);

            #pragma unroll
            for (int u = 0; u < 8; ++u)
                #pragma unroll
                for (int nf = 0; nf < 4; ++nf)
                    acc[nf] = __builtin_amdgcn_mfma_f32_16x16x32_bf16(
                        ah[u], wreg[u + 4][nf], acc[nf], 0, 0, 0);

            // D layout: col = lane&15, row = (lane>>4)*4 + reg.
            #pragma unroll
            for (int nf = 0; nf < 4; ++nf)
                #pragma unroll
                for (int q = 0; q < 4; ++q)
                    red[i & 1][w][kg * 4 + q][nf * 16 + l16] = acc[nf][q];
            __syncthreads();

            if ((l & 63) < 32) {
                f32x4 lo = blo, hi = bhi;
                #pragma unroll
                for (int p = 0; p < 4; ++p) {
                    lo += *reinterpret_cast<const f32x4*>(&red[i & 1][p][r1][c1]);
                    hi += *reinterpret_cast<const f32x4*>(&red[i & 1][p][r1][c1 + 4]);
                }
                cvu o;
                #pragma unroll
                for (int j = 0; j < 4; ++j) {
                    o.h[j]     = (__bf16)ftanh(lo[j]);
                    o.h[j + 4] = (__bf16)ftanh(hi[j]);
                }
                st16c(h1n + (m0 + r1) * HH + n0 + c1, o.f);
                if (i == SS - 1) {
                    float* op = h1out + (m0 + r1) * HH + n0 + c1;
                    #pragma unroll
                    for (int j = 0; j < 8; ++j)
                        op[j] = __bfloat162float(((__hip_bfloat16*)&o.h[j])[0]);
                }
            }
            wsignal(myf, (unsigned)(i + 1));
        }
    } else {
        // ---------------- h2 chain (trails h1) ----------------
        for (int j = 1; j <= SS; ++j) {
            const __bf16* h1j = h1r + (size_t)(j & 7) * BB * HH;
            const __bf16* h2p = h2r + (size_t)((j - 1) & 7) * BB * EE;
            __bf16*       h2n = h2r + (size_t)(j & 7) * BB * EE;

            wwait(f1s, 64, (unsigned)j);          // instant when trailing
            const __bf16* h1row = h1j + (m0 + l16) * HH;
            bf16x8 ah[8];
            #pragma unroll
            for (int t = 0; t < 8; ++t) {
                cvu t_; t_.f = ld16c(h1row + 32 * (w + 4 * t) + kg * 8);
                ah[t] = t_.h8;
            }
            if (j >= 2) wwait(f2s, 32, (unsigned)(j - 1));  // own hop
            const __bf16* h2row = h2p + (m0 + l16) * EE;
            bf16x8 a2[4];
            #pragma unroll
            for (int u = 0; u < 4; ++u) {
                cvu t_; t_.f = ld16c(h2row + 32 * (w + 4 * u) + kg * 8);
                a2[u] = t_.h8;
            }
            asm volatile("s_waitcnt vmcnt(0)" ::: "memory");
            __builtin_amdgcn_sched_barrier(0);

            f32x4 acc[4] = {{0,0,0,0},{0,0,0,0},{0,0,0,0},{0,0,0,0}};
            #pragma unroll
            for (int t = 0; t < 8; ++t)
                #pragma unroll
                for (int nf = 0; nf < 4; ++nf)
                    acc[nf] = __builtin_amdgcn_mfma_f32_16x16x32_bf16(
                        ah[t], wreg[t][nf], acc[nf], 0, 0, 0);
            #pragma unroll
            for (int u = 0; u < 4; ++u)
                #pragma unroll
                for (int nf = 0; nf < 4; ++nf)
                    acc[nf] = __builtin_amdgcn_mfma_f32_16x16x32_bf16(
                        a2[u], wreg[u + 8][nf], acc[nf], 0, 0, 0);

            #pragma unroll
            for (int nf = 0; nf < 4; ++nf)
                #pragma unroll
                for (int q = 0; q < 4; ++q)
                    red[j & 1][w][kg * 4 + q][nf * 16 + l16] = acc[nf][q];
            __syncthreads();

            if ((l & 63) < 32) {
                f32x4 lo = blo, hi = bhi;
                #pragma unroll
                for (int p = 0; p < 4; ++p) {
                    lo += *reinterpret_cast<const f32x4*>(&red[j & 1][p][r1][c1]);
                    hi += *reinterpret_cast<const f32x4*>(&red[j & 1][p][r1][c1 + 4]);
                }
                cvu o;
                #pragma unroll
                for (int q = 0; q < 4; ++q) {
                    o.h[q]     = (__bf16)ftanh(lo[q]);
                    o.h[q + 4] = (__bf16)ftanh(hi[q]);
                }
                st16c(h2n + (m0 + r1) * EE + n0 + c1, o.f);
                if (j == SS) {
                    float* op = h2out + (m0 + r1) * EE + n0 + c1;
                    #pragma unroll
                    for (int q = 0; q < 8; ++q)
                        op[q] = __bfloat162float(((__hip_bfloat16*)&o.h[q])[0]);
                }
            }
            wsignal(myf, (unsigned)j);
        }
    }
}

// Fallback per-step kernel (round-1 proven path), if cooperative launch fails.
__global__ __launch_bounds__(256) void step_kernel(
    const int* __restrict__ tok32,
    const float* __restrict__ embW,
    const float* __restrict__ b1, const float* __restrict__ b2,
    const __bf16* __restrict__ W1t, const __bf16* __restrict__ W2t,
    const __bf16* __restrict__ h1cur, __bf16* __restrict__ h1next,
    const __bf16* __restrict__ h2cur, __bf16* __restrict__ h2next,
    float* __restrict__ h1f32, float* __restrict__ h2f32,
    int t, int g1, int g2) {
    const int bid = blockIdx.x;
    const bool is1 = bid < 128;
    if (is1 ? (g1 == 0) : (g2 == 0)) return;
    const int rb = is1 ? bid : (bid - 128);
    const int mi = rb & 3;
    const int ni = rb >> 2;
    const int m0 = mi << 4;
    const int n0 = ni << 5;
    const int N = is1 ? HH : EE;
    const int tid = threadIdx.x;
    const int w = tid >> 6;
    const int l = tid & 63;
    const int l16 = l & 15;
    const int kg = l >> 4;

    __shared__ int tok_s[16];
    __shared__ float red[4][16][33];

    if (is1 && tid < 16) tok_s[tid] = tok32[(m0 + tid) * SS + t];
    __syncthreads();

    const __bf16* Wt = is1 ? W1t : W2t;
    f32x4 acc0 = {0.f, 0.f, 0.f, 0.f};
    f32x4 acc1 = {0.f, 0.f, 0.f, 0.f};
    const int row = m0 + l16;
    const int kb = w * 384;

    #pragma unroll 4
    for (int kk = 0; kk < 384; kk += 32) {
        const int k = kb + kk + kg * 8;
        bf16x8 a;
        if (is1) {
            if (k < EE) a = cvt8(embW + (size_t)tok_s[l16] * EE + k);
            else        a = load_bf8(h1cur + row * HH + (k - EE));
        } else {
            if (k < HH) a = load_bf8(h1cur + row * HH + k);
            else        a = load_bf8(h2cur + row * EE + (k - HH));
        }
        bf16x8 bf0 = load_bf8(Wt + (size_t)(n0 + l16) * KK + k);
        bf16x8 bf1 = load_bf8(Wt + (size_t)(n0 + 16 + l16) * KK + k);
        acc0 = __builtin_amdgcn_mfma_f32_16x16x32_bf16(a, bf0, acc0, 0, 0, 0);
        acc1 = __builtin_amdgcn_mfma_f32_16x16x32_bf16(a, bf1, acc1, 0, 0, 0);
    }

    #pragma unroll
    for (int i = 0; i < 4; ++i) {
        red[w][kg * 4 + i][l16]      = acc0[i];
        red[w][kg * 4 + i][16 + l16] = acc1[i];
    }
    __syncthreads();

    const float* bias = is1 ? b1 : b2;
    for (int c = tid; c < 512; c += 256) {
        int m = c >> 5, n = c & 31;
        float s = red[0][m][n] + red[1][m][n] + red[2][m][n] + red[3][m][n];
        s = tanhf(s + bias[n0 + n]);
        int gi = (m0 + m) * N + (n0 + n);
        if (is1) {
            h1next[gi] = (__bf16)s;
            if (h1f32) h1f32[gi] = s;
        } else {
            h2next[gi] = (__bf16)s;
            if (h2f32) h2f32[gi] = s;
        }
    }
}

// out[64, V] = h2 @ emb_W^T + out_b.
__global__ __launch_bounds__(256) void proj_kernel(
    const __bf16* __restrict__ h2bf,
    const float* __restrict__ embW,
    const float* __restrict__ outb,
    float* __restrict__ out) {
    const int v0 = blockIdx.x << 6;
    const int tid = threadIdx.x;
    const int w = tid >> 6;
    const int l = tid & 63;
    const int l16 = l & 15, kg = l >> 4;
    const int vcol = v0 + w * 16 + l16;
    const int vr = vcol < VV ? vcol : VV - 1;
    f32x4 acc[4] = {{0,0,0,0},{0,0,0,0},{0,0,0,0},{0,0,0,0}};
    #pragma unroll 2
    for (int k0 = 0; k0 < EE; k0 += 32) {
        const int k = k0 + kg * 8;
        bf16x8 bfr = cvt8(embW + (size_t)vr * EE + k);
        #pragma unroll
        for (int mf = 0; mf < 4; ++mf) {
            bf16x8 a = load_bf8(h2bf + (mf * 16 + l16) * EE + k);
            acc[mf] = __builtin_amdgcn_mfma_f32_16x16x32_bf16(a, bfr, acc[mf], 0, 0, 0);
        }
    }
    if (vcol < VV) {
        const float bb = outb[vcol];
        #pragma unroll
        for (int mf = 0; mf < 4; ++mf) {
            #pragma unroll
            for (int i = 0; i < 4; ++i) {
                int b = mf * 16 + kg * 4 + i;
                out[(size_t)b * VV + vcol] = acc[mf][i] + bb;
            }
        }
    }
}

extern "C" void kernel_launch(void* const* d_in, const int* in_sizes, int n_in,
                              void* d_out, int out_size, void* d_ws, size_t ws_size,
                              hipStream_t stream) {
    const void* seq      = d_in[0];
    const float* init_h1 = (const float*)d_in[1];
    const float* init_h2 = (const float*)d_in[2];
    const float* embW    = (const float*)d_in[3];
    const float* W1      = (const float*)d_in[4];
    const float* b1      = (const float*)d_in[5];
    const float* W2      = (const float*)d_in[6];
    const float* b2      = (const float*)d_in[7];
    const float* outb    = (const float*)d_in[8];
    float* out = (float*)d_out;

    char* ws = (char*)d_ws;
    int* tok = (int*)ws;                 ws += (size_t)BB * SS * 4;
    __bf16* W1t = (__bf16*)ws;           ws += (size_t)HH * KK * 2;
    __bf16* W2t = (__bf16*)ws;           ws += (size_t)EE * KK * 2;
    __bf16* h1r = (__bf16*)ws;           ws += (size_t)RING * BB * HH * 2;
    __bf16* h2r = (__bf16*)ws;           ws += (size_t)RING * BB * EE * 2;
    unsigned* bar = (unsigned*)ws;       ws += (size_t)4 * 96 * PADU * 4;

    hipLaunchKernelGGL(tokens_kernel, dim3(128), dim3(256), 0, stream, seq, tok, bar);
    hipLaunchKernelGGL(transpose_kernel, dim3((KK / 32) * (HH / 32)), dim3(256), 0, stream,
                       W1, W1t, KK, HH);
    hipLaunchKernelGGL(transpose_kernel, dim3((KK / 32) * (EE / 32)), dim3(256), 0, stream,
                       W2, W2t, KK, EE);
    // init states into ring slot 0
    hipLaunchKernelGGL(init_kernel, dim3(256), dim3(256), 0, stream,
                       init_h1, init_h2, h1r, h2r);

    float* h1out = out + (size_t)BB * VV;
    float* h2out = h1out + (size_t)BB * HH;

    const int* tok_c = tok;
    const __bf16* W1t_c = W1t;
    const __bf16* W2t_c = W2t;
    void* args[] = {
        (void*)&tok_c, (void*)&embW, (void*)&b1, (void*)&b2,
        (void*)&W1t_c, (void*)&W2t_c,
        (void*)&h1r, (void*)&h2r,
        (void*)&h1out, (void*)&h2out, (void*)&bar
    };
    hipError_t err = hipLaunchCooperativeKernel((void*)rnn_persist3, dim3(NWG), dim3(256),
                                                args, 0, stream);
    if (err != hipSuccess) {
        // Deterministic fallback: proven per-step path (round 1), ring slots 0/1.
        __bf16* h1bf[2] = {h1r, h1r + (size_t)BB * HH};
        __bf16* h2bf[2] = {h2r, h2r + (size_t)BB * EE};
        for (int t = 0; t <= SS; ++t) {
            int g1 = (t < SS) ? 1 : 0;
            int g2 = (t >= 1) ? 1 : 0;
            const __bf16* h1cur = h1bf[t & 1];
            __bf16* h1next      = h1bf[(t + 1) & 1];
            const __bf16* h2cur = h2bf[(t + 1) & 1];
            __bf16* h2next      = h2bf[t & 1];
            float* h1f = (t == SS - 1) ? h1out : nullptr;
            float* h2f = (t == SS) ? h2out : nullptr;
            hipLaunchKernelGGL(step_kernel, dim3(192), dim3(256), 0, stream,
                               tok, embW, b1, b2, W1t, W2t,
                               h1cur, h1next, h2cur, h2next, h1f, h2f, t, g1, g2);
        }
    }

    // h2_512 lives in ring slot 0 (512 % 8 == 0) on both paths.
    hipLaunchKernelGGL(proj_kernel, dim3((VV + 63) / 64), dim3(256), 0, stream,
                       h2r, embW, outb, out);
}